// Round 1
// baseline (1732.200 us; speedup 1.0000x reference)
//
#include <hip/hip_runtime.h>
#include <hip/hip_bf16.h>
#include <cstdint>
#include <cstddef>

// ---------------- problem constants ----------------
static constexpr int Bv  = 32;
static constexpr int Hv  = 56;
static constexpr int Wv  = 56;
static constexpr int Cv  = 384;
static constexpr int NHv = 12;
static constexpr int HDv = 32;
static constexpr int Nv  = 49;    // tokens per window
static constexpr int NWv = 64;    // windows per image
static constexpr int Mv  = Bv * NWv * Nv;   // 100352 token-rows
static constexpr int HID = 4 * Cv;          // 1536
static constexpr float SCALEv = 0.17677669529663687f;  // 32^-0.5

using bf16 = __hip_bfloat16;
typedef __bf16 bf16x8 __attribute__((ext_vector_type(8)));
typedef float  f32x4  __attribute__((ext_vector_type(4)));

// ---------------- weight transpose + bf16 cast: wt[n*K+k] = w[k*N+n] ----------------
__global__ __launch_bounds__(256)
void wt_kernel(const float* __restrict__ w, bf16* __restrict__ wt, int K, int N) {
    int idx = blockIdx.x * 256 + threadIdx.x;
    if (idx >= K * N) return;
    int n = idx / K, k = idx - n * K;
    wt[idx] = (bf16)w[(size_t)k * N + n];
}

// ---------------- LayerNorm (one wave per 384-ch row) ----------------
// MODE 0: output row r is in window order; gather source token through
//         cyclic shift (-3,-3) + window partition.  src fp32 -> dst bf16.
// MODE 1: direct row-to-row.
template <int MODE>
__global__ __launch_bounds__(256)
void ln_kernel(const float* __restrict__ src, const float* __restrict__ gam,
               const float* __restrict__ bet, bf16* __restrict__ dst) {
    const int wave = threadIdx.x >> 6, lane = threadIdx.x & 63;
    const int r = blockIdx.x * 4 + wave;             // output row
    size_t srow;
    if (MODE == 0) {
        int w  = r / 49, n = r - w * 49;
        int b  = w >> 6, win = w & 63;
        int hb = win >> 3, wb = win & 7;
        int ii = n / 7, jj = n - ii * 7;
        int hh = hb * 7 + ii + 3; if (hh >= 56) hh -= 56;   // shifted -> source row
        int ww = wb * 7 + jj + 3; if (ww >= 56) ww -= 56;
        srow = (size_t)b * 3136 + hh * 56 + ww;
    } else {
        srow = (size_t)r;
    }
    const float* p = src + srow * 384;
    float vals[6];
    float s = 0.f, s2 = 0.f;
#pragma unroll
    for (int t = 0; t < 6; ++t) {
        float v = p[t * 64 + lane];
        vals[t] = v; s += v; s2 += v * v;
    }
#pragma unroll
    for (int o = 32; o > 0; o >>= 1) {
        s  += __shfl_xor(s,  o, 64);
        s2 += __shfl_xor(s2, o, 64);
    }
    const float mu  = s * (1.f / 384.f);
    const float var = s2 * (1.f / 384.f) - mu * mu;
    const float rs  = rsqrtf(var + 1e-5f);
    bf16* q = dst + (size_t)r * 384;
#pragma unroll
    for (int t = 0; t < 6; ++t) {
        int e = t * 64 + lane;
        q[e] = (bf16)((vals[t] - mu) * rs * gam[e] + bet[e]);
    }
}

// ---------------- windowed attention: one block per (window, head) ----------------
__global__ __launch_bounds__(128)
void attn_kernel(const bf16* __restrict__ qkv, const float* __restrict__ btab,
                 bf16* __restrict__ o) {
    const int w = blockIdx.x;          // 0..2047
    const int h = blockIdx.y;          // 0..11
    const int tid = threadIdx.x;
    __shared__ float qs[49][33], ks[49][33], vs[49][33];
    __shared__ float S[49][49];
    __shared__ float bias[169];
    __shared__ int   label[49];

    const size_t rowbase = (size_t)w * 49;
    for (int idx = tid; idx < 49 * 32; idx += 128) {
        int n = idx >> 5, d = idx & 31;
        size_t base = (rowbase + n) * 1152 + h * 32 + d;
        qs[n][d] = (float)qkv[base] * SCALEv;
        ks[n][d] = (float)qkv[base + 384];
        vs[n][d] = (float)qkv[base + 768];
    }
    for (int idx = tid; idx < 169; idx += 128) bias[idx] = btab[idx * 12 + h];
    if (tid < 49) {
        int win = w & 63, hb = win >> 3, wb = win & 7;
        int i = tid / 7, j = tid - i * 7;
        int a = hb * 7 + i, c = wb * 7 + j;
        int rh = (a < 49) ? 0 : (a < 53 ? 1 : 2);
        int rw = (c < 49) ? 0 : (c < 53 ? 1 : 2);
        label[tid] = rh * 3 + rw;
    }
    __syncthreads();

    for (int idx = tid; idx < 49 * 49; idx += 128) {
        int n = idx / 49, m = idx - n * 49;
        float s = 0.f;
#pragma unroll
        for (int d = 0; d < 32; ++d) s += qs[n][d] * ks[m][d];
        int i1 = n / 7, j1 = n - i1 * 7;
        int i2 = m / 7, j2 = m - i2 * 7;
        s += bias[(i1 - i2 + 6) * 13 + (j1 - j2 + 6)];
        if (label[n] != label[m]) s -= 100.f;
        S[n][m] = s;
    }
    __syncthreads();

    if (tid < 49) {
        float mx = -1e30f;
        for (int m = 0; m < 49; ++m) mx = fmaxf(mx, S[tid][m]);
        float sum = 0.f;
        for (int m = 0; m < 49; ++m) {
            float e = __expf(S[tid][m] - mx);
            S[tid][m] = e; sum += e;
        }
        float inv = 1.f / sum;
        for (int m = 0; m < 49; ++m) S[tid][m] *= inv;
    }
    __syncthreads();

    for (int idx = tid; idx < 49 * 32; idx += 128) {
        int n = idx >> 5, d = idx & 31;
        float s = 0.f;
#pragma unroll
        for (int m = 0; m < 49; ++m) s += S[n][m] * vs[m][d];
        o[(rowbase + n) * 384 + h * 32 + d] = (bf16)s;
    }
}

// ---------------- bf16 MFMA GEMM, C = A[M,K] @ Bt[N,K]^T  (m97 structure) ----------
// 128x128 tile, BK=64, 256 threads = 4 waves in 2x2, each wave 4x4 subtiles of
// 16x16x32 MFMA.  Staging via global_load_lds width=16.
// EPI 0: outb = bf16(acc + bias)                                   (qkv)
// EPI 1: scatter window-reverse+unshift; outf[dst] = resid[dst]+acc+bias  (proj)
// EPI 2: outb = bf16(gelu(acc + bias))                             (fc1)
// EPI 3: outf[row] = resid[row] + acc + bias                       (fc2 -> d_out)
template <int EPI>
__global__ __launch_bounds__(256)
void gemm_bt(const bf16* __restrict__ A, const bf16* __restrict__ Bt,
             const float* __restrict__ bias, int N, int K,
             bf16* __restrict__ outb, float* __restrict__ outf,
             const float* __restrict__ resid) {
    __shared__ bf16 As[128 * 64];
    __shared__ bf16 Bs[128 * 64];
    const int tid  = threadIdx.x;
    const int lane = tid & 63, wave = tid >> 6;
    const int quad = lane >> 4, l16 = lane & 15;
    const int wm = wave >> 1, wn = wave & 1;
    const long m0 = (long)blockIdx.y * 128;
    const long n0 = (long)blockIdx.x * 128;

    f32x4 acc[4][4] = {};

    for (int k0 = 0; k0 < K; k0 += 64) {
        __syncthreads();   // previous iter's LDS reads done before overwrite
#pragma unroll
        for (int it = 0; it < 4; ++it) {
            int e = it * 256 + tid;            // 16B-chunk index, 0..1023
            int row = e >> 3;                  // 0..127
            int col = (e & 7) << 3;            // 0..56
            __builtin_amdgcn_global_load_lds(
                (const __attribute__((address_space(1))) unsigned int*)(A + (size_t)(m0 + row) * K + k0 + col),
                (__attribute__((address_space(3))) unsigned int*)(As + (size_t)e * 8),
                16, 0, 0);
            __builtin_amdgcn_global_load_lds(
                (const __attribute__((address_space(1))) unsigned int*)(Bt + (size_t)(n0 + row) * K + k0 + col),
                (__attribute__((address_space(3))) unsigned int*)(Bs + (size_t)e * 8),
                16, 0, 0);
        }
        __syncthreads();   // drain global_load_lds + barrier
#pragma unroll
        for (int kk = 0; kk < 64; kk += 32) {
            bf16x8 af[4], bfr[4];
#pragma unroll
            for (int i = 0; i < 4; ++i)
                af[i] = *(const bf16x8*)(As + (wm * 64 + i * 16 + l16) * 64 + kk + quad * 8);
#pragma unroll
            for (int j = 0; j < 4; ++j)
                bfr[j] = *(const bf16x8*)(Bs + (wn * 64 + j * 16 + l16) * 64 + kk + quad * 8);
#pragma unroll
            for (int i = 0; i < 4; ++i)
#pragma unroll
                for (int j = 0; j < 4; ++j)
                    acc[i][j] = __builtin_amdgcn_mfma_f32_16x16x32_bf16(af[i], bfr[j], acc[i][j], 0, 0, 0);
        }
    }

    // epilogue: C/D layout col=lane&15, row=quad*4+reg
#pragma unroll
    for (int i = 0; i < 4; ++i) {
        const long mbase = m0 + wm * 64 + i * 16 + quad * 4;
#pragma unroll
        for (int j = 0; j < 4; ++j) {
            const int col = (int)n0 + wn * 64 + j * 16 + l16;
            const float bv = bias[col];
            f32x4 r = acc[i][j];
#pragma unroll
            for (int t = 0; t < 4; ++t) {
                const long m = mbase + t;
                float val = r[t] + bv;
                if constexpr (EPI == 0) {
                    outb[(size_t)m * N + col] = (bf16)val;
                } else if constexpr (EPI == 1) {
                    int w  = (int)(m / 49), n = (int)(m - (long)w * 49);
                    int b  = w >> 6, win = w & 63;
                    int hb = win >> 3, wb = win & 7;
                    int ii = n / 7, jj = n - ii * 7;
                    int hh = hb * 7 + ii + 3; if (hh >= 56) hh -= 56;  // reverse shift
                    int ww = wb * 7 + jj + 3; if (ww >= 56) ww -= 56;
                    size_t dst = ((size_t)b * 3136 + hh * 56 + ww) * 384 + col;
                    outf[dst] = resid[dst] + val;
                } else if constexpr (EPI == 2) {
                    float g = 0.5f * val * (1.0f + erff(val * 0.70710678118654752f));
                    outb[(size_t)m * N + col] = (bf16)g;
                } else {
                    size_t oo = (size_t)m * N + col;
                    outf[oo] = resid[oo] + val;
                }
            }
        }
    }
}

// ---------------- launch ----------------
extern "C" void kernel_launch(void* const* d_in, const int* in_sizes, int n_in,
                              void* d_out, int out_size, void* d_ws, size_t ws_size,
                              hipStream_t stream) {
    const float* x     = (const float*)d_in[0];
    const float* n1g   = (const float*)d_in[1];
    const float* n1b   = (const float*)d_in[2];
    const float* qkvw  = (const float*)d_in[3];
    const float* qkvb  = (const float*)d_in[4];
    const float* btab  = (const float*)d_in[5];
    const float* projw = (const float*)d_in[6];
    const float* projb = (const float*)d_in[7];
    const float* n2g   = (const float*)d_in[8];
    const float* n2b   = (const float*)d_in[9];
    const float* fc1w  = (const float*)d_in[10];
    const float* fc1b  = (const float*)d_in[11];
    const float* fc2w  = (const float*)d_in[12];
    const float* fc2b  = (const float*)d_in[13];
    float* out = (float*)d_out;

    char* ws = (char*)d_ws;
    size_t off = 0;
    auto take = [&](size_t bytes) {
        char* p = ws + off;
        off += (bytes + 255) & ~(size_t)255;
        return p;
    };
    // arena (~543 MB total)
    bf16* qkv_wt  = (bf16*)take((size_t)1152 * 384 * 2);
    bf16* proj_wt = (bf16*)take((size_t)384 * 384 * 2);
    bf16* fc1_wt  = (bf16*)take((size_t)1536 * 384 * 2);
    bf16* fc2_wt  = (bf16*)take((size_t)384 * 1536 * 2);
    bf16* qkv_buf = (bf16*)take((size_t)Mv * 1152 * 2);   // 231 MB
    bf16* o_buf   = (bf16*)take((size_t)Mv * 384 * 2);    // 77 MB (adjacent to qkv)
    bf16* hw_buf  = (bf16*)take((size_t)Mv * 384 * 2);    // 77 MB, later reused as x1n
    float* x1     = (float*)take((size_t)Mv * 384 * 4);   // 154 MB
    bf16* g_buf   = qkv_buf;   // 308 MB: spans (dead) qkv+o regions for fc1 output
    bf16* x1n     = hw_buf;    // hw dead after qkv GEMM

    // 1. weight transpose + bf16 cast
    wt_kernel<<<(384 * 1152 + 255) / 256, 256, 0, stream>>>(qkvw,  qkv_wt,  384, 1152);
    wt_kernel<<<(384 * 384  + 255) / 256, 256, 0, stream>>>(projw, proj_wt, 384, 384);
    wt_kernel<<<(384 * 1536 + 255) / 256, 256, 0, stream>>>(fc1w,  fc1_wt,  384, 1536);
    wt_kernel<<<(1536 * 384 + 255) / 256, 256, 0, stream>>>(fc2w,  fc2_wt,  1536, 384);
    // 2. LN1 fused with cyclic shift + window partition (gather)
    ln_kernel<0><<<Mv / 4, 256, 0, stream>>>(x, n1g, n1b, hw_buf);
    // 3. qkv = hw @ qkv_w + b
    gemm_bt<0><<<dim3(1152 / 128, Mv / 128), 256, 0, stream>>>(
        hw_buf, qkv_wt, qkvb, 1152, 384, qkv_buf, nullptr, nullptr);
    // 4. windowed attention (rel-bias + shift mask + softmax)
    attn_kernel<<<dim3(2048, 12), 128, 0, stream>>>(qkv_buf, btab, o_buf);
    // 5. proj + window reverse + reverse shift + residual -> x1 (fp32)
    gemm_bt<1><<<dim3(384 / 128, Mv / 128), 256, 0, stream>>>(
        o_buf, proj_wt, projb, 384, 384, nullptr, x1, x);
    // 6. LN2
    ln_kernel<1><<<Mv / 4, 256, 0, stream>>>(x1, n2g, n2b, x1n);
    // 7. fc1 + exact GELU
    gemm_bt<2><<<dim3(1536 / 128, Mv / 128), 256, 0, stream>>>(
        x1n, fc1_wt, fc1b, 1536, 384, g_buf, nullptr, nullptr);
    // 8. fc2 + residual -> out
    gemm_bt<3><<<dim3(384 / 128, Mv / 128), 256, 0, stream>>>(
        g_buf, fc2_wt, fc2b, 384, 1536, nullptr, out, x1);
}

// Round 2
// 1325.519 us; speedup vs baseline: 1.3068x; 1.3068x over previous
//
#include <hip/hip_runtime.h>
#include <hip/hip_bf16.h>
#include <cstdint>
#include <cstddef>

// ---------------- problem constants ----------------
static constexpr int Bv  = 32;
static constexpr int Cv  = 384;
static constexpr int Nv  = 49;    // tokens per window
static constexpr int Mv  = 32 * 64 * 49;   // 100352 token-rows
static constexpr float SCALEv = 0.17677669529663687f;  // 32^-0.5

using bf16 = __hip_bfloat16;
typedef __bf16 bf16x8 __attribute__((ext_vector_type(8)));
typedef float  f32x4  __attribute__((ext_vector_type(4)));

// ---------------- weight transpose + bf16 cast: wt[n*K+k] = w[k*N+n] ----------------
__global__ __launch_bounds__(256)
void wt_kernel(const float* __restrict__ w, bf16* __restrict__ wt, int K, int N) {
    int idx = blockIdx.x * 256 + threadIdx.x;
    if (idx >= K * N) return;
    int n = idx / K, k = idx - n * K;
    wt[idx] = (bf16)w[(size_t)k * N + n];
}

// ---------------- combined rel-bias + shift-mask table ----------------
// BMt[cls][h][col 64][row 64] f32.  cls = (hb==7)*2 + (wb==7).
// col >= 49 -> -1e30 (kills padded K columns); row clamped to 48.
__global__ __launch_bounds__(256)
void bm_kernel(const float* __restrict__ btab, float* __restrict__ bmt) {
    const int cls = blockIdx.x, h = blockIdx.y;
    for (int idx = threadIdx.x; idx < 4096; idx += 256) {
        int col = idx >> 6, row = idx & 63;
        float v;
        if (col >= 49) {
            v = -1e30f;
        } else {
            int n = row < 49 ? row : 48;
            int m = col;
            int i1 = n / 7, j1 = n - i1 * 7;
            int i2 = m / 7, j2 = m - i2 * 7;
            v = btab[((i1 - i2 + 6) * 13 + (j1 - j2 + 6)) * 12 + h];
            int lh1 = (cls & 2) ? (i1 < 4 ? 1 : 2) : 0;
            int lw1 = (cls & 1) ? (j1 < 4 ? 1 : 2) : 0;
            int lh2 = (cls & 2) ? (i2 < 4 ? 1 : 2) : 0;
            int lw2 = (cls & 1) ? (j2 < 4 ? 1 : 2) : 0;
            if ((lh1 * 3 + lw1) != (lh2 * 3 + lw2)) v += -100.f;
        }
        bmt[((size_t)(cls * 12 + h) * 64 + col) * 64 + row] = v;
    }
}

// ---------------- LayerNorm (one wave per 384-ch row) ----------------
template <int MODE>
__global__ __launch_bounds__(256)
void ln_kernel(const float* __restrict__ src, const float* __restrict__ gam,
               const float* __restrict__ bet, bf16* __restrict__ dst) {
    const int wave = threadIdx.x >> 6, lane = threadIdx.x & 63;
    const int r = blockIdx.x * 4 + wave;             // output row
    size_t srow;
    if (MODE == 0) {
        int w  = r / 49, n = r - w * 49;
        int b  = w >> 6, win = w & 63;
        int hb = win >> 3, wb = win & 7;
        int ii = n / 7, jj = n - ii * 7;
        int hh = hb * 7 + ii + 3; if (hh >= 56) hh -= 56;   // shifted -> source row
        int ww = wb * 7 + jj + 3; if (ww >= 56) ww -= 56;
        srow = (size_t)b * 3136 + hh * 56 + ww;
    } else {
        srow = (size_t)r;
    }
    const float* p = src + srow * 384;
    float vals[6];
    float s = 0.f, s2 = 0.f;
#pragma unroll
    for (int t = 0; t < 6; ++t) {
        float v = p[t * 64 + lane];
        vals[t] = v; s += v; s2 += v * v;
    }
#pragma unroll
    for (int o = 32; o > 0; o >>= 1) {
        s  += __shfl_xor(s,  o, 64);
        s2 += __shfl_xor(s2, o, 64);
    }
    const float mu  = s * (1.f / 384.f);
    const float var = s2 * (1.f / 384.f) - mu * mu;
    const float rs  = rsqrtf(var + 1e-5f);
    bf16* q = dst + (size_t)r * 384;
#pragma unroll
    for (int t = 0; t < 6; ++t) {
        int e = t * 64 + lane;
        q[e] = (bf16)((vals[t] - mu) * rs * gam[e] + bet[e]);
    }
}

// ---------------- MFMA windowed attention: one wave per (window, head) -------------
// Q pre-scaled by SCALE in qkv-GEMM epilogue.  S tiles 64x64 (pad 49->64),
// BM table supplies bias+mask (-1e30 on padded cols -> P cols exactly 0).
__global__ __launch_bounds__(64)
void attn_kernel(const bf16* __restrict__ qkv, const float* __restrict__ bmt,
                 bf16* __restrict__ o) {
    const int w = blockIdx.x;          // 0..2047
    const int h = blockIdx.y;          // 0..11
    const int lane = threadIdx.x;
    const int quad = lane >> 4, l16 = lane & 15;
    __shared__ bf16 Vt[32][72];        // V^T, cols 49..63 zeroed
    __shared__ bf16 Ps[64][72];        // P round-trip (C-layout -> A-layout)

    const size_t rowbase = (size_t)w * 49;

    // stage V^T (coalesced global read, transposed LDS write)
    for (int idx = lane; idx < 49 * 16; idx += 64) {
        int row = idx >> 4, dp = (idx & 15) << 1;
        const bf16* src = qkv + (rowbase + row) * 1152 + 768 + h * 32 + dp;
        Vt[dp][row]     = src[0];
        Vt[dp + 1][row] = src[1];
    }
    for (int idx = lane; idx < 512; idx += 64) {     // zero cols 49..63
        int d = idx >> 4, c = idx & 15;
        if (c) Vt[d][48 + c] = (bf16)0.f;
    }

    // ---- S = Q K^T : fragments straight from global (contiguous in k) ----
    f32x4 acc[4][4] = {};
    bf16x8 af[4], bfr[4];
#pragma unroll
    for (int i = 0; i < 4; ++i) {
        int row = 16 * i + l16; if (row > 48) row = 48;
        af[i] = *(const bf16x8*)(qkv + (rowbase + row) * 1152 + h * 32 + quad * 8);
    }
#pragma unroll
    for (int j = 0; j < 4; ++j) {
        int row = 16 * j + l16; if (row > 48) row = 48;
        bfr[j] = *(const bf16x8*)(qkv + (rowbase + row) * 1152 + 384 + h * 32 + quad * 8);
    }
#pragma unroll
    for (int i = 0; i < 4; ++i)
#pragma unroll
        for (int j = 0; j < 4; ++j)
            acc[i][j] = __builtin_amdgcn_mfma_f32_16x16x32_bf16(af[i], bfr[j], acc[i][j], 0, 0, 0);

    // ---- bias + mask + softmax (rows = 16i + quad*4 + t), write P to LDS ----
    const int cls = (((w & 63) >= 56) ? 2 : 0) + (((w & 7) == 7) ? 1 : 0);
    const float* bmbase = bmt + (size_t)(cls * 12 + h) * 4096;
    float inv[4][4];
#pragma unroll
    for (int i = 0; i < 4; ++i) {
        f32x4 bm[4];
#pragma unroll
        for (int j = 0; j < 4; ++j)
            bm[j] = *(const f32x4*)(bmbase + (16 * j + l16) * 64 + 16 * i + quad * 4);
#pragma unroll
        for (int t = 0; t < 4; ++t) {
            float v0 = acc[i][0][t] + bm[0][t];
            float v1 = acc[i][1][t] + bm[1][t];
            float v2 = acc[i][2][t] + bm[2][t];
            float v3 = acc[i][3][t] + bm[3][t];
            float mx = fmaxf(fmaxf(v0, v1), fmaxf(v2, v3));
#pragma unroll
            for (int ofs = 1; ofs < 16; ofs <<= 1) mx = fmaxf(mx, __shfl_xor(mx, ofs, 64));
            float p0 = __expf(v0 - mx), p1 = __expf(v1 - mx);
            float p2 = __expf(v2 - mx), p3 = __expf(v3 - mx);
            float s = (p0 + p1) + (p2 + p3);
#pragma unroll
            for (int ofs = 1; ofs < 16; ofs <<= 1) s += __shfl_xor(s, ofs, 64);
            inv[i][t] = 1.f / s;
            int prow = 16 * i + quad * 4 + t;
            Ps[prow][l16]      = (bf16)p0;
            Ps[prow][16 + l16] = (bf16)p1;
            Ps[prow][32 + l16] = (bf16)p2;
            Ps[prow][48 + l16] = (bf16)p3;
        }
    }
    __syncthreads();

    // ---- O = P V ----
    f32x4 oacc[4][2] = {};
    bf16x8 vb[2][2];
#pragma unroll
    for (int jn = 0; jn < 2; ++jn)
#pragma unroll
        for (int ks = 0; ks < 2; ++ks)
            vb[jn][ks] = *(const bf16x8*)(&Vt[16 * jn + l16][32 * ks + quad * 8]);
#pragma unroll
    for (int i = 0; i < 4; ++i) {
#pragma unroll
        for (int ks = 0; ks < 2; ++ks) {
            bf16x8 pa = *(const bf16x8*)(&Ps[16 * i + l16][32 * ks + quad * 8]);
#pragma unroll
            for (int jn = 0; jn < 2; ++jn)
                oacc[i][jn] = __builtin_amdgcn_mfma_f32_16x16x32_bf16(pa, vb[jn][ks], oacc[i][jn], 0, 0, 0);
        }
    }

    // ---- scale by 1/sum, store valid rows ----
#pragma unroll
    for (int i = 0; i < 4; ++i) {
        int nbase = 16 * i + quad * 4;
#pragma unroll
        for (int t = 0; t < 4; ++t) {
            int n = nbase + t;
            if (n < 49) {
                bf16* dst = o + (rowbase + n) * 384 + h * 32;
                dst[l16]      = (bf16)(oacc[i][0][t] * inv[i][t]);
                dst[16 + l16] = (bf16)(oacc[i][1][t] * inv[i][t]);
            }
        }
    }
}

// ---------------- bf16 MFMA GEMM, C = A[M,K] @ Bt[N,K]^T  (m97 structure) ----------
// EPI 0: outb = bf16((acc+bias) * (col<384 ? SCALE : 1))            (qkv, q pre-scaled)
// EPI 1: scatter window-reverse+unshift; outf[dst] = resid[dst]+acc+bias  (proj)
// EPI 2: outb = bf16(gelu(acc + bias))                              (fc1)
// EPI 3: outf[row] = resid[row] + acc + bias                        (fc2 -> d_out)
template <int EPI>
__global__ __launch_bounds__(256)
void gemm_bt(const bf16* __restrict__ A, const bf16* __restrict__ Bt,
             const float* __restrict__ bias, int N, int K,
             bf16* __restrict__ outb, float* __restrict__ outf,
             const float* __restrict__ resid) {
    __shared__ bf16 As[128 * 64];
    __shared__ bf16 Bs[128 * 64];
    const int tid  = threadIdx.x;
    const int lane = tid & 63, wave = tid >> 6;
    const int quad = lane >> 4, l16 = lane & 15;
    const int wm = wave >> 1, wn = wave & 1;
    const long m0 = (long)blockIdx.y * 128;
    const long n0 = (long)blockIdx.x * 128;

    f32x4 acc[4][4] = {};

    for (int k0 = 0; k0 < K; k0 += 64) {
        __syncthreads();
#pragma unroll
        for (int it = 0; it < 4; ++it) {
            int e = it * 256 + tid;
            int row = e >> 3;
            int col = (e & 7) << 3;
            __builtin_amdgcn_global_load_lds(
                (const __attribute__((address_space(1))) unsigned int*)(A + (size_t)(m0 + row) * K + k0 + col),
                (__attribute__((address_space(3))) unsigned int*)(As + (size_t)e * 8),
                16, 0, 0);
            __builtin_amdgcn_global_load_lds(
                (const __attribute__((address_space(1))) unsigned int*)(Bt + (size_t)(n0 + row) * K + k0 + col),
                (__attribute__((address_space(3))) unsigned int*)(Bs + (size_t)e * 8),
                16, 0, 0);
        }
        __syncthreads();
#pragma unroll
        for (int kk = 0; kk < 64; kk += 32) {
            bf16x8 af[4], bfr[4];
#pragma unroll
            for (int i = 0; i < 4; ++i)
                af[i] = *(const bf16x8*)(As + (wm * 64 + i * 16 + l16) * 64 + kk + quad * 8);
#pragma unroll
            for (int j = 0; j < 4; ++j)
                bfr[j] = *(const bf16x8*)(Bs + (wn * 64 + j * 16 + l16) * 64 + kk + quad * 8);
#pragma unroll
            for (int i = 0; i < 4; ++i)
#pragma unroll
                for (int j = 0; j < 4; ++j)
                    acc[i][j] = __builtin_amdgcn_mfma_f32_16x16x32_bf16(af[i], bfr[j], acc[i][j], 0, 0, 0);
        }
    }

#pragma unroll
    for (int i = 0; i < 4; ++i) {
        const long mbase = m0 + wm * 64 + i * 16 + quad * 4;
#pragma unroll
        for (int j = 0; j < 4; ++j) {
            const int col = (int)n0 + wn * 64 + j * 16 + l16;
            const float bv = bias[col];
            f32x4 r = acc[i][j];
#pragma unroll
            for (int t = 0; t < 4; ++t) {
                const long m = mbase + t;
                float val = r[t] + bv;
                if constexpr (EPI == 0) {
                    float sc = (col < 384) ? SCALEv : 1.0f;
                    outb[(size_t)m * N + col] = (bf16)(val * sc);
                } else if constexpr (EPI == 1) {
                    int w  = (int)(m / 49), n = (int)(m - (long)w * 49);
                    int b  = w >> 6, win = w & 63;
                    int hb = win >> 3, wb = win & 7;
                    int ii = n / 7, jj = n - ii * 7;
                    int hh = hb * 7 + ii + 3; if (hh >= 56) hh -= 56;
                    int ww = wb * 7 + jj + 3; if (ww >= 56) ww -= 56;
                    size_t dst = ((size_t)b * 3136 + hh * 56 + ww) * 384 + col;
                    outf[dst] = resid[dst] + val;
                } else if constexpr (EPI == 2) {
                    float g = 0.5f * val * (1.0f + erff(val * 0.70710678118654752f));
                    outb[(size_t)m * N + col] = (bf16)g;
                } else {
                    size_t oo = (size_t)m * N + col;
                    outf[oo] = resid[oo] + val;
                }
            }
        }
    }
}

// ---------------- launch ----------------
extern "C" void kernel_launch(void* const* d_in, const int* in_sizes, int n_in,
                              void* d_out, int out_size, void* d_ws, size_t ws_size,
                              hipStream_t stream) {
    const float* x     = (const float*)d_in[0];
    const float* n1g   = (const float*)d_in[1];
    const float* n1b   = (const float*)d_in[2];
    const float* qkvw  = (const float*)d_in[3];
    const float* qkvb  = (const float*)d_in[4];
    const float* btab  = (const float*)d_in[5];
    const float* projw = (const float*)d_in[6];
    const float* projb = (const float*)d_in[7];
    const float* n2g   = (const float*)d_in[8];
    const float* n2b   = (const float*)d_in[9];
    const float* fc1w  = (const float*)d_in[10];
    const float* fc1b  = (const float*)d_in[11];
    const float* fc2w  = (const float*)d_in[12];
    const float* fc2b  = (const float*)d_in[13];
    float* out = (float*)d_out;

    char* ws = (char*)d_ws;
    size_t off = 0;
    auto take = [&](size_t bytes) {
        char* p = ws + off;
        off += (bytes + 255) & ~(size_t)255;
        return p;
    };
    bf16* qkv_wt  = (bf16*)take((size_t)1152 * 384 * 2);
    bf16* proj_wt = (bf16*)take((size_t)384 * 384 * 2);
    bf16* fc1_wt  = (bf16*)take((size_t)1536 * 384 * 2);
    bf16* fc2_wt  = (bf16*)take((size_t)384 * 1536 * 2);
    float* bmt    = (float*)take((size_t)4 * 12 * 64 * 64 * 4);
    bf16* qkv_buf = (bf16*)take((size_t)Mv * 1152 * 2);   // 231 MB
    bf16* o_buf   = (bf16*)take((size_t)Mv * 384 * 2);    // 77 MB
    bf16* hw_buf  = (bf16*)take((size_t)Mv * 384 * 2);    // 77 MB, later reused as x1n
    float* x1     = (float*)take((size_t)Mv * 384 * 4);   // 154 MB
    bf16* g_buf   = qkv_buf;   // fc1 output spans dead qkv+o regions
    bf16* x1n     = hw_buf;    // hw dead after qkv GEMM

    wt_kernel<<<(384 * 1152 + 255) / 256, 256, 0, stream>>>(qkvw,  qkv_wt,  384, 1152);
    wt_kernel<<<(384 * 384  + 255) / 256, 256, 0, stream>>>(projw, proj_wt, 384, 384);
    wt_kernel<<<(384 * 1536 + 255) / 256, 256, 0, stream>>>(fc1w,  fc1_wt,  384, 1536);
    wt_kernel<<<(1536 * 384 + 255) / 256, 256, 0, stream>>>(fc2w,  fc2_wt,  1536, 384);
    bm_kernel<<<dim3(4, 12), 256, 0, stream>>>(btab, bmt);
    ln_kernel<0><<<Mv / 4, 256, 0, stream>>>(x, n1g, n1b, hw_buf);
    gemm_bt<0><<<dim3(1152 / 128, Mv / 128), 256, 0, stream>>>(
        hw_buf, qkv_wt, qkvb, 1152, 384, qkv_buf, nullptr, nullptr);
    attn_kernel<<<dim3(2048, 12), 64, 0, stream>>>(qkv_buf, bmt, o_buf);
    gemm_bt<1><<<dim3(384 / 128, Mv / 128), 256, 0, stream>>>(
        o_buf, proj_wt, projb, 384, 384, nullptr, x1, x);
    ln_kernel<1><<<Mv / 4, 256, 0, stream>>>(x1, n2g, n2b, x1n);
    gemm_bt<2><<<dim3(1536 / 128, Mv / 128), 256, 0, stream>>>(
        x1n, fc1_wt, fc1b, 1536, 384, g_buf, nullptr, nullptr);
    gemm_bt<3><<<dim3(384 / 128, Mv / 128), 256, 0, stream>>>(
        g_buf, fc2_wt, fc2b, 384, 1536, nullptr, out, x1);
}